// Round 2
// baseline (374.107 us; speedup 1.0000x reference)
//
#include <hip/hip_runtime.h>

// Problem geometry (fixed by setup_inputs)
static constexpr int BS     = 64;
static constexpr int C_TS   = 128;
static constexpr int C_CTS  = 256;
static constexpr int T      = 2048;
static constexpr int N_CAT  = 32;
static constexpr int N_CONT = 64;

#define MASK_P 0.15f
#define REP_P  0.8f
#define RND_HI 0.9f   // f32(0.8+0.1) == 0.9f

// masked[b,c,t] = rep ? 0 : (rnd ? x[b,c,r_idx[b,t]] : x[b,c,t])
// rep = (u_mask<0.15) & (u_act<0.8); rnd = (u_mask<0.15) & (0.8<=u_act<0.9)
template <int C>
__global__ __launch_bounds__(256) void mask_ts_kernel(
    const float* __restrict__ x,
    const float* __restrict__ u_mask,   // [BS, T]
    const float* __restrict__ u_act,    // [BS, T]
    const int*   __restrict__ r_idx,    // [BS, T]
    float* __restrict__ out) {
    constexpr int T4 = T / 4;
    const int i = blockIdx.x * blockDim.x + threadIdx.x;   // float4 index, grid exact
    const int t4 = i % T4;
    const int bc = i / T4;        // b*C + c
    const int b  = bc / C;
    const int bt4 = b * T4 + t4;

    float4 xv = reinterpret_cast<const float4*>(x)[i];
    float4 um = reinterpret_cast<const float4*>(u_mask)[bt4];
    float4 ua = reinterpret_cast<const float4*>(u_act)[bt4];
    int4   ri = reinterpret_cast<const int4*>(r_idx)[bt4];

    const float* xrow = x + (size_t)bc * T;

    float r[4]   = {xv.x, xv.y, xv.z, xv.w};
    float ums[4] = {um.x, um.y, um.z, um.w};
    float uas[4] = {ua.x, ua.y, ua.z, ua.w};
    int   ris[4] = {ri.x, ri.y, ri.z, ri.w};

#pragma unroll
    for (int j = 0; j < 4; ++j) {
        if (ums[j] < MASK_P) {
            if (uas[j] < REP_P)        r[j] = 0.0f;          // replace -> zero
            else if (uas[j] < RND_HI)  r[j] = xrow[ris[j]];  // random  -> swap within row
            // else keep
        }
    }
    reinterpret_cast<float4*>(out)[i] = make_float4(r[0], r[1], r[2], r[3]);
}

// Static categorical (int -> emitted as float) and static continuous
// (replace -> per-feature batch mean; random -> other batch row, same feature)
__global__ __launch_bounds__(256) void statics_kernel(
    const int*   __restrict__ x_cat,       // [BS, N_CAT]
    const float* __restrict__ u_cat_mask,
    const float* __restrict__ u_cat_act,
    const int*   __restrict__ r_cat_val,
    const float* __restrict__ x_cont,      // [BS, N_CONT]
    const float* __restrict__ u_cont_mask,
    const float* __restrict__ u_cont_act,
    const int*   __restrict__ r_cont_idx,
    float* __restrict__ out_cat,
    float* __restrict__ out_cont) {
    const int i = blockIdx.x * blockDim.x + threadIdx.x;
    const int NCAT = BS * N_CAT;
    if (i < NCAT) {
        float um = u_cat_mask[i], ua = u_cat_act[i];
        int v = x_cat[i];
        if (um < MASK_P) {
            if (ua < REP_P)       v = 0;
            else if (ua < RND_HI) v = r_cat_val[i];
        }
        out_cat[i] = (float)v;
    } else if (i < NCAT + BS * N_CONT) {
        const int j = i - NCAT;
        const int f = j & (N_CONT - 1);
        float um = u_cont_mask[j], ua = u_cont_act[j];
        float v = x_cont[j];
        if (um < MASK_P) {
            if (ua < REP_P) {
                // per-feature mean over batch (sequential f32 sum, matches jnp tol)
                float s = 0.0f;
                for (int b = 0; b < BS; ++b) s += x_cont[b * N_CONT + f];
                v = s * (1.0f / BS);
            } else if (ua < RND_HI) {
                v = x_cont[r_cont_idx[j] * N_CONT + f];
            }
        }
        out_cont[j] = v;
    }
}

extern "C" void kernel_launch(void* const* d_in, const int* in_sizes, int n_in,
                              void* d_out, int out_size, void* d_ws, size_t ws_size,
                              hipStream_t stream) {
    const float* x_ts       = (const float*)d_in[0];
    const float* x_ts_cat   = (const float*)d_in[1];
    const int*   x_cat      = (const int*)  d_in[2];
    const float* x_cont     = (const float*)d_in[3];
    const float* u_ts_mask  = (const float*)d_in[4];
    const float* u_ts_act   = (const float*)d_in[5];
    const int*   r_ts_idx   = (const int*)  d_in[6];
    const float* u_cts_mask = (const float*)d_in[7];
    const float* u_cts_act  = (const float*)d_in[8];
    const int*   r_cts_idx  = (const int*)  d_in[9];
    const float* u_cat_mask = (const float*)d_in[10];
    const float* u_cat_act  = (const float*)d_in[11];
    const int*   r_cat_val  = (const int*)  d_in[12];
    const float* u_cont_mask= (const float*)d_in[13];
    const float* u_cont_act = (const float*)d_in[14];
    const int*   r_cont_idx = (const int*)  d_in[15];

    float* out_ts   = (float*)d_out;
    float* out_cts  = out_ts  + (size_t)BS * C_TS  * T;   // 16,777,216
    float* out_cat  = out_cts + (size_t)BS * C_CTS * T;   // +33,554,432
    float* out_cont = out_cat + BS * N_CAT;               // +2,048

    // Big streaming kernels: one float4 per lane, exact grids.
    {
        const int total4 = BS * C_TS * (T / 4);           // 4,194,304
        mask_ts_kernel<C_TS><<<total4 / 256, 256, 0, stream>>>(
            x_ts, u_ts_mask, u_ts_act, r_ts_idx, out_ts);
    }
    {
        const int total4 = BS * C_CTS * (T / 4);          // 8,388,608
        mask_ts_kernel<C_CTS><<<total4 / 256, 256, 0, stream>>>(
            x_ts_cat, u_cts_mask, u_cts_act, r_cts_idx, out_cts);
    }
    // Tiny statics kernel (6144 elements).
    {
        const int total = BS * N_CAT + BS * N_CONT;       // 6,144
        statics_kernel<<<(total + 255) / 256, 256, 0, stream>>>(
            x_cat, u_cat_mask, u_cat_act, r_cat_val,
            x_cont, u_cont_mask, u_cont_act, r_cont_idx,
            out_cat, out_cont);
    }
}

// Round 5
// 367.670 us; speedup vs baseline: 1.0175x; 1.0175x over previous
//
#include <hip/hip_runtime.h>

// Problem geometry (fixed by setup_inputs)
static constexpr int BS     = 64;
static constexpr int C_TS   = 128;
static constexpr int C_CTS  = 256;
static constexpr int T      = 2048;
static constexpr int T4     = T / 4;          // 512 (pow2 -> shift math)
static constexpr int N_CAT  = 32;
static constexpr int N_CONT = 64;

static constexpr int TOT4_TS  = BS * C_TS  * T4;   // 4,194,304 float4s
static constexpr int TOT4_CTS = BS * C_CTS * T4;   // 8,388,608 float4s
static constexpr int NB_TS    = TOT4_TS  / 256;    // 16,384 blocks
static constexpr int NB_CTS   = TOT4_CTS / 256;    // 32,768 blocks
static constexpr int NB_BIG   = NB_TS + NB_CTS;    // 49,152
static constexpr int NB_STAT  = (BS * N_CAT + BS * N_CONT) / 256;  // 24

#define MASK_P 0.15f
#define REP_P  0.8f
#define RND_HI 0.9f   // f32(0.8+0.1) == 0.9f

// Native clang vector types — required by __builtin_nontemporal_store
// (HIP's float4 is a class type the builtin rejects).
typedef float f32x4 __attribute__((ext_vector_type(4)));
typedef int   i32x4 __attribute__((ext_vector_type(4)));

// One fused dispatch:
//   blocks [0, NB_TS)            -> masked x_ts      (C=128)
//   blocks [NB_TS, NB_BIG)       -> masked x_ts_cat  (C=256)
//   blocks [NB_BIG, NB_BIG+24)   -> static cat + cont outputs
__global__ __launch_bounds__(256) void fused_mlm_kernel(
    const float* __restrict__ x_ts,
    const float* __restrict__ x_cts,
    const float* __restrict__ u_ts_mask,  const float* __restrict__ u_ts_act,
    const int*   __restrict__ r_ts_idx,
    const float* __restrict__ u_cts_mask, const float* __restrict__ u_cts_act,
    const int*   __restrict__ r_cts_idx,
    const int*   __restrict__ x_cat,
    const float* __restrict__ u_cat_mask, const float* __restrict__ u_cat_act,
    const int*   __restrict__ r_cat_val,
    const float* __restrict__ x_cont,
    const float* __restrict__ u_cont_mask, const float* __restrict__ u_cont_act,
    const int*   __restrict__ r_cont_idx,
    float* __restrict__ out_ts, float* __restrict__ out_cts,
    float* __restrict__ out_cat, float* __restrict__ out_cont) {
    const int bid = blockIdx.x;

    if (bid < NB_BIG) {
        // ---- big streaming masked-TS path (uniform per-block region select) ----
        int i;                      // float4 index within the selected tensor
        const float* x;
        float* out;
        const float* um_p; const float* ua_p; const int* ri_p;
        int log2C;
        if (bid < NB_TS) {
            i = bid * 256 + threadIdx.x;
            x = x_ts; out = out_ts;
            um_p = u_ts_mask; ua_p = u_ts_act; ri_p = r_ts_idx;
            log2C = 7;            // C = 128
        } else {
            i = (bid - NB_TS) * 256 + threadIdx.x;
            x = x_cts; out = out_cts;
            um_p = u_cts_mask; ua_p = u_cts_act; ri_p = r_cts_idx;
            log2C = 8;            // C = 256
        }
        const int t4  = i & (T4 - 1);          // i % 512
        const int bc  = i >> 9;                // i / 512  (b*C + c)
        const int b   = bc >> log2C;
        const int bt4 = (b << 9) + t4;

        f32x4 xv = reinterpret_cast<const f32x4*>(x)[i];
        f32x4 um = reinterpret_cast<const f32x4*>(um_p)[bt4];
        f32x4 ua = reinterpret_cast<const f32x4*>(ua_p)[bt4];
        i32x4 ri = reinterpret_cast<const i32x4*>(ri_p)[bt4];

        const float* xrow = x + (size_t)bc * T;

        f32x4 r = xv;
#pragma unroll
        for (int j = 0; j < 4; ++j) {
            if (um[j] < MASK_P) {
                if (ua[j] < REP_P)        r[j] = 0.0f;          // replace -> zero
                else if (ua[j] < RND_HI)  r[j] = xrow[ri[j]];   // random  -> swap in-row
                // else keep
            }
        }
        // Output is never re-read: non-temporal store keeps L2 for decisions/gathers.
        __builtin_nontemporal_store(r, reinterpret_cast<f32x4*>(out) + i);
    } else {
        // ---- tiny statics path: 6144 scalars across 24 blocks ----
        const int gid = (bid - NB_BIG) * 256 + threadIdx.x;
        const int NCAT = BS * N_CAT;
        if (gid < NCAT) {
            float um = u_cat_mask[gid], ua = u_cat_act[gid];
            int v = x_cat[gid];
            if (um < MASK_P) {
                if (ua < REP_P)       v = 0;
                else if (ua < RND_HI) v = r_cat_val[gid];
            }
            out_cat[gid] = (float)v;
        } else {
            const int j = gid - NCAT;            // [0, BS*N_CONT)
            const int f = j & (N_CONT - 1);
            float um = u_cont_mask[j], ua = u_cont_act[j];
            float v = x_cont[j];
            if (um < MASK_P) {
                if (ua < REP_P) {
                    float s = 0.0f;              // per-feature batch mean
                    for (int b = 0; b < BS; ++b) s += x_cont[b * N_CONT + f];
                    v = s * (1.0f / BS);
                } else if (ua < RND_HI) {
                    v = x_cont[r_cont_idx[j] * N_CONT + f];
                }
            }
            out_cont[j] = v;
        }
    }
}

extern "C" void kernel_launch(void* const* d_in, const int* in_sizes, int n_in,
                              void* d_out, int out_size, void* d_ws, size_t ws_size,
                              hipStream_t stream) {
    const float* x_ts       = (const float*)d_in[0];
    const float* x_ts_cat   = (const float*)d_in[1];
    const int*   x_cat      = (const int*)  d_in[2];
    const float* x_cont     = (const float*)d_in[3];
    const float* u_ts_mask  = (const float*)d_in[4];
    const float* u_ts_act   = (const float*)d_in[5];
    const int*   r_ts_idx   = (const int*)  d_in[6];
    const float* u_cts_mask = (const float*)d_in[7];
    const float* u_cts_act  = (const float*)d_in[8];
    const int*   r_cts_idx  = (const int*)  d_in[9];
    const float* u_cat_mask = (const float*)d_in[10];
    const float* u_cat_act  = (const float*)d_in[11];
    const int*   r_cat_val  = (const int*)  d_in[12];
    const float* u_cont_mask= (const float*)d_in[13];
    const float* u_cont_act = (const float*)d_in[14];
    const int*   r_cont_idx = (const int*)  d_in[15];

    float* out_ts   = (float*)d_out;
    float* out_cts  = out_ts  + (size_t)BS * C_TS  * T;   // +16,777,216
    float* out_cat  = out_cts + (size_t)BS * C_CTS * T;   // +33,554,432
    float* out_cont = out_cat + BS * N_CAT;               // +2,048

    fused_mlm_kernel<<<NB_BIG + NB_STAT, 256, 0, stream>>>(
        x_ts, x_ts_cat,
        u_ts_mask, u_ts_act, r_ts_idx,
        u_cts_mask, u_cts_act, r_cts_idx,
        x_cat, u_cat_mask, u_cat_act, r_cat_val,
        x_cont, u_cont_mask, u_cont_act, r_cont_idx,
        out_ts, out_cts, out_cat, out_cont);
}